// Round 13
// baseline (138.188 us; speedup 1.0000x reference)
//
#include <hip/hip_runtime.h>

#define HH 128
#define WW 128
#define HW (HH*WW)

// ---- ws layout (f32 indices) ----
#define O_H1   0u         // u16 NHWC h1 (4,128,128,64) = 2097152 f32
#define O_H2   2097152u   // u16 NHWC h2 (4,128,128,32) = 1048576 f32
#define O_BTA2 3145728u   // u16[32*576]  Bt offconv2 [co][kk*64+ci]
#define O_BTB2 3154944u   // u16[32*576]  Bt deform2  [co][n*64+ci]
#define O_BTA3 3164160u   // u16[32*288]  Bt offconv3 [co][kk*32+ci]
#define O_BTB3 3168768u   // u16[16*288]  Bt deform3  [co][n*32+ci]
#define O_BO2  3171072u
#define O_B2   3171090u
#define O_BO3  3171122u
#define O_B3   3171140u

typedef unsigned short u16;
typedef unsigned int   u32;
typedef short  short8 __attribute__((ext_vector_type(8)));
typedef float  f32x4  __attribute__((ext_vector_type(4)));
typedef float  f32x2  __attribute__((ext_vector_type(2)));

__device__ __forceinline__ float bf2f(u16 h) {
    return __uint_as_float(((u32)h) << 16);
}
__device__ __forceinline__ u16 f2bf(float f) {   // round-to-nearest-even
    u32 u = __float_as_uint(f);
    return (u16)((u + 0x7FFFu + ((u >> 16) & 1u)) >> 16);
}
__device__ __forceinline__ u32 cvtpk(float lo, float hi) {  // 2xf32 -> 2xbf16
    u32 r;
    asm("v_cvt_pk_bf16_f32 %0, %1, %2" : "=v"(r) : "v"(lo), "v"(hi));
    return r;
}
__device__ __forceinline__ void unpk2(uint4 v, f32x2* f) {
    f[0] = (f32x2){__uint_as_float(v.x << 16), __uint_as_float(v.x & 0xFFFF0000u)};
    f[1] = (f32x2){__uint_as_float(v.y << 16), __uint_as_float(v.y & 0xFFFF0000u)};
    f[2] = (f32x2){__uint_as_float(v.z << 16), __uint_as_float(v.z & 0xFFFF0000u)};
    f[3] = (f32x2){__uint_as_float(v.w << 16), __uint_as_float(v.w & 0xFFFF0000u)};
}
// bilinear on 8 packed bf16 channels -> bf16 A-fragment (packed f32 math)
__device__ __forceinline__ short8 bilerp8(const uint4* Bv, float wy, float wx) {
    f32x2 f00[4], f01[4], f10[4], f11[4];
    unpk2(Bv[0], f00); unpk2(Bv[1], f01); unpk2(Bv[2], f10); unpk2(Bv[3], f11);
    f32x2 wy2 = {wy, wy}, wx2 = {wx, wx};
    union { u32 u[4]; short8 s; } cv;
    #pragma unroll
    for (int j = 0; j < 4; ++j) {
        f32x2 top = __builtin_elementwise_fma(wx2, f01[j] - f00[j], f00[j]);
        f32x2 bot = __builtin_elementwise_fma(wx2, f11[j] - f10[j], f10[j]);
        f32x2 v   = __builtin_elementwise_fma(wy2, bot - top, top);
        cv.u[j] = cvtpk(v[0], v[1]);
    }
    return cv.s;
}
__device__ __forceinline__ float ldm(const void* p, int i, bool bf) {
    return bf ? bf2f(((const u16*)p)[i]) : ((const float*)p)[i];
}
// wave-uniform dtype flag from first 64 words of x (see round-2 notes)
__device__ __forceinline__ bool wave_flag(const u32* xu) {
    u32 w = xu[threadIdx.x & 63];
    u32 lo = w & 0xFFFFu;
    u32 e = (lo >> 7) & 0xFFu;
    bool ok = (lo != 0u) && (e >= 100u) && (e <= 140u);
    return __popcll(__ballot(ok)) > 32;
}

// =====================================================================
// conv1 + weight-prep merged. bid<4096: conv1 (x -> h1 NHWC bf16, relu).
// bid>=4096: weights -> bf16 MFMA-transposed Bt[col][K].
// =====================================================================
__global__ __launch_bounds__(256) void conv1_prep(
        const u32* xu, const void* x, const void* w1, const void* b1,
        const void* wo2, const void* bo2, const void* w2, const void* b2,
        const void* wo3, const void* bo3, const void* w3, const void* b3,
        float* ws) {
    bool bf = wave_flag(xu);
    int bid = blockIdx.x;
    if (bid >= 4096) {
        int i = (bid - 4096) * 256 + threadIdx.x;
        u16* btA2 = (u16*)(ws + O_BTA2);
        u16* btB2 = (u16*)(ws + O_BTB2);
        u16* btA3 = (u16*)(ws + O_BTA3);
        u16* btB3 = (u16*)(ws + O_BTB3);
        if (i < 18432) {               // K = kk*64+ci / n*64+ci
            int co = i / 576, K = i % 576, k9 = K >> 6, ci = K & 63;
            btA2[i] = f2bf(co < 18 ? ldm(wo2, (co * 64 + ci) * 9 + k9, bf) : 0.f);
            btB2[i] = f2bf(ldm(w2, (co * 64 + ci) * 9 + k9, bf));
        }
        if (i < 9216) {
            int co = i / 288, K = i % 288, k9 = K >> 5, ci = K & 31;
            btA3[i] = f2bf(co < 18 ? ldm(wo3, (co * 32 + ci) * 9 + k9, bf) : 0.f);
        }
        if (i < 4608) {
            int co = i / 288, K = i % 288, k9 = K >> 5, ci = K & 31;
            btB3[i] = f2bf(co < 4 ? ldm(w3, (co * 32 + ci) * 9 + k9, bf) : 0.f);
        }
        if (i < 18) ws[O_BO2 + i] = ldm(bo2, i, bf);
        if (i < 32) ws[O_B2 + i]  = ldm(b2, i, bf);
        if (i < 18) ws[O_BO3 + i] = ldm(bo3, i, bf);
        if (i < 4)  ws[O_B3 + i]  = ldm(b3, i, bf);
        return;
    }
    u16* out = (u16*)(ws + O_H1);
    int idx = bid * 256 + threadIdx.x;
    int cg = idx & 15; int t = idx >> 4;
    int xw = t & 127;  t >>= 7;
    int yh = t & 127;  int b = t >> 7;
    float xv[9];
    #pragma unroll
    for (int ky = 0; ky < 3; ++ky) {
        int yy = yh + ky - 1;
        #pragma unroll
        for (int kx = 0; kx < 3; ++kx) {
            int xx = xw + kx - 1;
            xv[ky * 3 + kx] =
                ((unsigned)yy < 128u && (unsigned)xx < 128u)
                    ? ldm(x, b * HW + yy * WW + xx, bf) : 0.f;
        }
    }
    u16 o[4];
    #pragma unroll
    for (int j = 0; j < 4; ++j) {
        int co = cg * 4 + j;
        float acc = ldm(b1, co, bf);
        #pragma unroll
        for (int k = 0; k < 9; ++k)
            acc = fmaf(ldm(w1, co * 9 + k, bf), xv[k], acc);
        o[j] = f2bf(fmaxf(acc, 0.f));
    }
    uint2 pk;
    pk.x = (u32)o[0] | ((u32)o[1] << 16);
    pk.y = (u32)o[2] | ((u32)o[3] << 16);
    *(uint2*)&out[(((size_t)b * 128 + yh) * 128 + xw) * 64 + cg * 4] = pk;
}

// =====================================================================
// fused_mid: offconv(64->18) + deform + conv(64->32) + relu, MFMA.
// NO LDS window — all feature gathers go to L1/L2 (h1 is L2-resident).
// Block = 256 thr (4 waves) = 1 row x 64 px. LDS = 5 KB transpose aux.
// =====================================================================
__global__ __launch_bounds__(256) void fused_mid(
        const u16* __restrict__ h1, const u16* __restrict__ btA,
        const u16* __restrict__ btB, const float* __restrict__ bo,
        const float* __restrict__ bd, u16* __restrict__ h2) {
    __shared__ float aux[1280];     // offb[64][20]; overlay cb u16[64][32]
    int tid = threadIdx.x;
    int lane = tid & 63, p = lane & 15, q = lane >> 4;
    int wv = __builtin_amdgcn_readfirstlane(tid >> 6);
    int bid = blockIdx.x;
    int hx = bid & 1, yh = (bid >> 1) & 127, b = bid >> 8;
    int xwb = hx * 64;
    int xx = wv * 16 + p;           // pixel within the 64-px strip
    const u16* h1b = h1 + (size_t)b * HW * 64;

    // ---- phase A: offset conv as MFMA (K = kk*64+ci, 18 chunks), 2-deep ----
#define LDA_M(c, dst) do { \
        const int kk_ = (c) >> 1, ky_ = kk_ / 3, kx_ = kk_ % 3; \
        int gy_ = yh + ky_ - 1, gc_ = xwb + xx + kx_ - 1; \
        int ci0_ = (((c) & 1) << 5) + 8 * q; \
        dst = (short8){0, 0, 0, 0, 0, 0, 0, 0}; \
        if ((unsigned)gy_ < 128u && (unsigned)gc_ < 128u) \
            dst = *(const short8*)(h1b + ((size_t)(gy_ * 128 + gc_)) * 64 + ci0_); \
    } while (0)

    f32x4 a0 = {0.f, 0.f, 0.f, 0.f}, a1 = {0.f, 0.f, 0.f, 0.f};
    {
        short8 avb[2], n0b[2], n1b[2];
        LDA_M(0, avb[0]); LDA_M(1, avb[1]);
        n0b[0] = *(const short8*)(btA + p * 576 + 8 * q);
        n1b[0] = *(const short8*)(btA + (16 + p) * 576 + 8 * q);
        n0b[1] = *(const short8*)(btA + p * 576 + 32 + 8 * q);
        n1b[1] = *(const short8*)(btA + (16 + p) * 576 + 32 + 8 * q);
        #pragma unroll
        for (int c = 0; c < 18; ++c) {
            short8 av = avb[c & 1], b0 = n0b[c & 1], b1 = n1b[c & 1];
            if (c + 2 < 18) {
                LDA_M(c + 2, avb[c & 1]);
                n0b[c & 1] = *(const short8*)(btA + p * 576 + 32 * (c + 2) + 8 * q);
                n1b[c & 1] = *(const short8*)(btA + (16 + p) * 576 + 32 * (c + 2) + 8 * q);
            }
            a0 = __builtin_amdgcn_mfma_f32_16x16x32_bf16(av, b0, a0, 0, 0, 0);
            a1 = __builtin_amdgcn_mfma_f32_16x16x32_bf16(av, b1, a1, 0, 0, 0);
        }
    }
#undef LDA_M
    #pragma unroll
    for (int r = 0; r < 4; ++r) {            // C: row=q*4+r, col=p
        int row = wv * 16 + q * 4 + r;
        aux[row * 20 + p] = a0[r] + bo[p];
        if (p < 2) aux[row * 20 + 16 + p] = a1[r] + bo[16 + p];
    }
    __syncthreads();

    // ---- geometry (per lane, for its pixel xx) ----
    float wyA[9], wxA[9]; int pk[9];
    #pragma unroll
    for (int n = 0; n < 9; ++n) {
        float py  = aux[xx * 20 + n]     + (float)(n / 3 - 1 + yh);
        float pxf = aux[xx * 20 + 9 + n] + (float)(n % 3 - 1 + xwb + xx);
        py  = fminf(fmaxf(py, 0.f), 127.f);
        pxf = fminf(fmaxf(pxf, 0.f), 127.f);
        float y0f = floorf(py), x0f = floorf(pxf);
        int y0 = (int)y0f, x0 = (int)x0f;
        int dy = (y0 < 127) ? 1 : 0, dx = (x0 < 127) ? 1 : 0;
        wyA[n] = py - y0f; wxA[n] = pxf - x0f;
        pk[n] = (y0 * 128 + x0) | (dx << 14) | (dy << 15);
    }
    __syncthreads();

    // ---- phase B: deform GEMM as MFMA, global gathers, 3-buf pipelined ----
#define LOADCHUNK_M(c, B) do { \
        int pp_ = pk[(c) >> 1]; \
        int ci0_ = (((c) & 1) << 5) + 8 * q; \
        size_t base_ = (size_t)(pp_ & 16383) * 64 + ci0_; \
        int dxo_ = ((pp_ >> 14) & 1) * 64; \
        int dyo_ = ((pp_ >> 15) & 1) * 8192; \
        B[0] = *(const uint4*)(h1b + base_); \
        B[1] = *(const uint4*)(h1b + base_ + dxo_); \
        B[2] = *(const uint4*)(h1b + base_ + dyo_); \
        B[3] = *(const uint4*)(h1b + base_ + dyo_ + dxo_); \
    } while (0)

    f32x4 c0 = {0.f, 0.f, 0.f, 0.f}, c1 = {0.f, 0.f, 0.f, 0.f};
    {
        uint4 wbuf[3][4];
        short8 n0b[2], n1b[2];
        n0b[0] = *(const short8*)(btB + p * 576 + 8 * q);
        n1b[0] = *(const short8*)(btB + (16 + p) * 576 + 8 * q);
        n0b[1] = *(const short8*)(btB + p * 576 + 32 + 8 * q);
        n1b[1] = *(const short8*)(btB + (16 + p) * 576 + 32 + 8 * q);
        LOADCHUNK_M(0, wbuf[0]);
        LOADCHUNK_M(1, wbuf[1]);
        #pragma unroll
        for (int c = 0; c < 18; ++c) {
            short8 b0 = n0b[c & 1], b1 = n1b[c & 1];
            if (c + 2 < 18) {
                n0b[c & 1] = *(const short8*)(btB + p * 576 + 32 * (c + 2) + 8 * q);
                n1b[c & 1] = *(const short8*)(btB + (16 + p) * 576 + 32 * (c + 2) + 8 * q);
                LOADCHUNK_M(c + 2, wbuf[(c + 2) % 3]);
            }
            short8 av = bilerp8(wbuf[c % 3], wyA[c >> 1], wxA[c >> 1]);
            c0 = __builtin_amdgcn_mfma_f32_16x16x32_bf16(av, b0, c0, 0, 0, 0);
            c1 = __builtin_amdgcn_mfma_f32_16x16x32_bf16(av, b1, c1, 0, 0, 0);
        }
    }
#undef LOADCHUNK_M

    // ---- C -> LDS bounce -> coalesced NHWC h2 stores ----
    u16* cb = (u16*)aux;
    #pragma unroll
    for (int r = 0; r < 4; ++r) {
        int px = wv * 16 + q * 4 + r;
        cb[px * 32 + p]      = f2bf(fmaxf(c0[r] + bd[p], 0.f));
        cb[px * 32 + 16 + p] = f2bf(fmaxf(c1[r] + bd[16 + p], 0.f));
    }
    __syncthreads();
    {
        int px = tid >> 2, co8 = (tid & 3) * 8;
        *(uint4*)&h2[(((size_t)b * 128 + yh) * 128 + xwb + px) * 32 + co8] =
            *(const uint4*)&cb[px * 32 + co8];
    }
}

// =====================================================================
// fused_final: offconv(32->18) + deform + conv(32->4) + pixel shuffle.
// NO LDS window; h2 is L2-resident. Block = 256 thr = 1 row x 64 px.
// =====================================================================
__global__ __launch_bounds__(256) void fused_final(
        const u16* __restrict__ h2, const u16* __restrict__ btA,
        const u16* __restrict__ btB, const float* __restrict__ bo,
        const float* __restrict__ bd, const u32* __restrict__ xu,
        float* __restrict__ outf, u32* __restrict__ outb) {
    __shared__ float aux[1280];     // offb[64][20]; overlay ob[64][5]
    bool bf = wave_flag(xu);
    int tid = threadIdx.x;
    int lane = tid & 63, p = lane & 15, q = lane >> 4;
    int wv = __builtin_amdgcn_readfirstlane(tid >> 6);
    int bid = blockIdx.x;
    int hx = bid & 1, yh = (bid >> 1) & 127, b = bid >> 8;
    int xwb = hx * 64;
    int xx = wv * 16 + p;
    const u16* h2b = h2 + (size_t)b * HW * 32;

    // ---- phase A (K = kk*32+ci, 9 chunks), 2-deep ----
#define LDA_F(c, dst) do { \
        const int ky_ = (c) / 3, kx_ = (c) % 3; \
        int gy_ = yh + ky_ - 1, gc_ = xwb + xx + kx_ - 1; \
        dst = (short8){0, 0, 0, 0, 0, 0, 0, 0}; \
        if ((unsigned)gy_ < 128u && (unsigned)gc_ < 128u) \
            dst = *(const short8*)(h2b + ((size_t)(gy_ * 128 + gc_)) * 32 + 8 * q); \
    } while (0)

    f32x4 a0 = {0.f, 0.f, 0.f, 0.f}, a1 = {0.f, 0.f, 0.f, 0.f};
    {
        short8 avb[2], n0b[2], n1b[2];
        LDA_F(0, avb[0]); LDA_F(1, avb[1]);
        n0b[0] = *(const short8*)(btA + p * 288 + 8 * q);
        n1b[0] = *(const short8*)(btA + (16 + p) * 288 + 8 * q);
        n0b[1] = *(const short8*)(btA + p * 288 + 32 + 8 * q);
        n1b[1] = *(const short8*)(btA + (16 + p) * 288 + 32 + 8 * q);
        #pragma unroll
        for (int c = 0; c < 9; ++c) {
            short8 av = avb[c & 1], b0 = n0b[c & 1], b1 = n1b[c & 1];
            if (c + 2 < 9) {
                LDA_F(c + 2, avb[c & 1]);
                n0b[c & 1] = *(const short8*)(btA + p * 288 + 32 * (c + 2) + 8 * q);
                n1b[c & 1] = *(const short8*)(btA + (16 + p) * 288 + 32 * (c + 2) + 8 * q);
            }
            a0 = __builtin_amdgcn_mfma_f32_16x16x32_bf16(av, b0, a0, 0, 0, 0);
            a1 = __builtin_amdgcn_mfma_f32_16x16x32_bf16(av, b1, a1, 0, 0, 0);
        }
    }
#undef LDA_F
    #pragma unroll
    for (int r = 0; r < 4; ++r) {
        int row = wv * 16 + q * 4 + r;
        aux[row * 20 + p] = a0[r] + bo[p];
        if (p < 2) aux[row * 20 + 16 + p] = a1[r] + bo[16 + p];
    }
    __syncthreads();

    // ---- geometry ----
    float wyA[9], wxA[9]; int pk[9];
    #pragma unroll
    for (int n = 0; n < 9; ++n) {
        float py  = aux[xx * 20 + n]     + (float)(n / 3 - 1 + yh);
        float pxf = aux[xx * 20 + 9 + n] + (float)(n % 3 - 1 + xwb + xx);
        py  = fminf(fmaxf(py, 0.f), 127.f);
        pxf = fminf(fmaxf(pxf, 0.f), 127.f);
        float y0f = floorf(py), x0f = floorf(pxf);
        int y0 = (int)y0f, x0 = (int)x0f;
        int dy = (y0 < 127) ? 1 : 0, dx = (x0 < 127) ? 1 : 0;
        wyA[n] = py - y0f; wxA[n] = pxf - x0f;
        pk[n] = (y0 * 128 + x0) | (dx << 14) | (dy << 15);
    }
    __syncthreads();

    // ---- phase B (K = n*32+ci, 9 chunks), global gathers, 3-buf ----
#define LOADCHUNK_F(c, B) do { \
        int pp_ = pk[(c)]; \
        size_t base_ = (size_t)(pp_ & 16383) * 32 + 8 * q; \
        int dxo_ = ((pp_ >> 14) & 1) * 32; \
        int dyo_ = ((pp_ >> 15) & 1) * 4096; \
        B[0] = *(const uint4*)(h2b + base_); \
        B[1] = *(const uint4*)(h2b + base_ + dxo_); \
        B[2] = *(const uint4*)(h2b + base_ + dyo_); \
        B[3] = *(const uint4*)(h2b + base_ + dyo_ + dxo_); \
    } while (0)

    f32x4 c0 = {0.f, 0.f, 0.f, 0.f};
    {
        uint4 wbuf[3][4];
        short8 n0b[2];
        n0b[0] = *(const short8*)(btB + p * 288 + 8 * q);
        n0b[1] = *(const short8*)(btB + p * 288 + 32 + 8 * q);
        LOADCHUNK_F(0, wbuf[0]);
        LOADCHUNK_F(1, wbuf[1]);
        #pragma unroll
        for (int c = 0; c < 9; ++c) {
            short8 b0 = n0b[c & 1];
            if (c + 2 < 9) {
                n0b[c & 1] = *(const short8*)(btB + p * 288 + 32 * (c + 2) + 8 * q);
                LOADCHUNK_F(c + 2, wbuf[(c + 2) % 3]);
            }
            short8 av = bilerp8(wbuf[c % 3], wyA[c], wxA[c]);
            c0 = __builtin_amdgcn_mfma_f32_16x16x32_bf16(av, b0, c0, 0, 0, 0);
        }
    }
#undef LOADCHUNK_F

    // ---- output bounce + pixel shuffle ----
    if (p < 4) {
        #pragma unroll
        for (int r = 0; r < 4; ++r)
            aux[(wv * 16 + q * 4 + r) * 5 + p] = c0[r] + bd[p];
    }
    __syncthreads();
    if (tid < 64) {
        float o0 = aux[tid * 5 + 0], o1 = aux[tid * 5 + 1];
        float o2 = aux[tid * 5 + 2], o3 = aux[tid * 5 + 3];
        int xw = xwb + tid;
        if (bf) {
            u32 p0 = ((u32)f2bf(o1) << 16) | (u32)f2bf(o0);
            u32 p1 = ((u32)f2bf(o3) << 16) | (u32)f2bf(o2);
            outb[(size_t)(b * 256 + 2 * yh) * 128 + xw]     = p0;
            outb[(size_t)(b * 256 + 2 * yh + 1) * 128 + xw] = p1;
        } else {
            size_t r0 = (size_t)(b * 256 + 2 * yh) * 256 + 2 * xw;
            outf[r0]       = o0;
            outf[r0 + 1]   = o1;
            outf[r0 + 256] = o2;
            outf[r0 + 257] = o3;
        }
    }
}

extern "C" void kernel_launch(void* const* d_in, const int* in_sizes, int n_in,
                              void* d_out, int out_size, void* d_ws, size_t ws_size,
                              hipStream_t stream) {
    float* ws = (float*)d_ws;
    const u32* xu = (const u32*)d_in[0];
    conv1_prep<<<4168, 256, 0, stream>>>(
        xu, d_in[0], d_in[1], d_in[2], d_in[3], d_in[4], d_in[5], d_in[6],
        d_in[7], d_in[8], d_in[9], d_in[10], ws);
    fused_mid<<<1024, 256, 0, stream>>>(
        (const u16*)(ws + O_H1), (const u16*)(ws + O_BTA2),
        (const u16*)(ws + O_BTB2), ws + O_BO2, ws + O_B2, (u16*)(ws + O_H2));
    fused_final<<<1024, 256, 0, stream>>>(
        (const u16*)(ws + O_H2), (const u16*)(ws + O_BTA3),
        (const u16*)(ws + O_BTB3), ws + O_BO3, ws + O_B3,
        xu, (float*)d_out, (u32*)d_out);
}

// Round 14
// 92.635 us; speedup vs baseline: 1.4918x; 1.4918x over previous
//
#include <hip/hip_runtime.h>

#define HH 128
#define WW 128
#define HW (HH*WW)

// ---- ws layout (f32 indices) ----
#define O_H1   0u         // u16 NHWC h1 (4,128,128,64) = 2097152 f32
#define O_H2   2097152u   // u16 NHWC h2 (4,128,128,32) = 1048576 f32
#define O_BTA2 3145728u   // u16[18*2*64*8]  offconv2, [c][tile][lane][e]
#define O_BTB2 3154944u   // u16[18*2*64*8]  deform2,  [c][tile][lane][e]
#define O_BTA3 3164160u   // u16[9*2*64*8]   offconv3, [c][tile][lane][e]
#define O_BTB3 3168768u   // u16[9*64*8]     deform3,  [c][lane][e]
#define O_BO2  3171072u
#define O_B2   3171090u
#define O_BO3  3171122u
#define O_B3   3171140u

typedef unsigned short u16;
typedef unsigned int   u32;
typedef short  short8 __attribute__((ext_vector_type(8)));
typedef float  f32x4  __attribute__((ext_vector_type(4)));
typedef float  f32x2  __attribute__((ext_vector_type(2)));

__device__ __forceinline__ float bf2f(u16 h) {
    return __uint_as_float(((u32)h) << 16);
}
__device__ __forceinline__ u16 f2bf(float f) {   // round-to-nearest-even
    u32 u = __float_as_uint(f);
    return (u16)((u + 0x7FFFu + ((u >> 16) & 1u)) >> 16);
}
__device__ __forceinline__ u32 cvtpk(float lo, float hi) {  // 2xf32 -> 2xbf16
    u32 r;
    asm("v_cvt_pk_bf16_f32 %0, %1, %2" : "=v"(r) : "v"(lo), "v"(hi));
    return r;
}
__device__ __forceinline__ void unpk2(uint4 v, f32x2* f) {
    f[0] = (f32x2){__uint_as_float(v.x << 16), __uint_as_float(v.x & 0xFFFF0000u)};
    f[1] = (f32x2){__uint_as_float(v.y << 16), __uint_as_float(v.y & 0xFFFF0000u)};
    f[2] = (f32x2){__uint_as_float(v.z << 16), __uint_as_float(v.z & 0xFFFF0000u)};
    f[3] = (f32x2){__uint_as_float(v.w << 16), __uint_as_float(v.w & 0xFFFF0000u)};
}
// bilinear on 8 packed bf16 channels -> bf16 A-fragment (packed f32 math)
__device__ __forceinline__ short8 bilerp8(const uint4* Bv, float wy, float wx) {
    f32x2 f00[4], f01[4], f10[4], f11[4];
    unpk2(Bv[0], f00); unpk2(Bv[1], f01); unpk2(Bv[2], f10); unpk2(Bv[3], f11);
    f32x2 wy2 = {wy, wy}, wx2 = {wx, wx};
    union { u32 u[4]; short8 s; } cv;
    #pragma unroll
    for (int j = 0; j < 4; ++j) {
        f32x2 top = __builtin_elementwise_fma(wx2, f01[j] - f00[j], f00[j]);
        f32x2 bot = __builtin_elementwise_fma(wx2, f11[j] - f10[j], f10[j]);
        f32x2 v   = __builtin_elementwise_fma(wy2, bot - top, top);
        cv.u[j] = cvtpk(v[0], v[1]);
    }
    return cv.s;
}
__device__ __forceinline__ float ldm(const void* p, int i, bool bf) {
    return bf ? bf2f(((const u16*)p)[i]) : ((const float*)p)[i];
}
// wave-uniform dtype flag from first 64 words of x (see round-2 notes)
__device__ __forceinline__ bool wave_flag(const u32* xu) {
    u32 w = xu[threadIdx.x & 63];
    u32 lo = w & 0xFFFFu;
    u32 e = (lo >> 7) & 0xFFu;
    bool ok = (lo != 0u) && (e >= 100u) && (e <= 140u);
    return __popcll(__ballot(ok)) > 32;
}

// =====================================================================
// conv1 + weight-prep merged. bid<4096: conv1 (x -> h1 NHWC bf16, relu).
// bid>=4096: weights -> bf16, per-chunk-contiguous [c][tile][lane][e]
// so each wave's per-chunk B-fragment load is one dense 1KB block.
// =====================================================================
__global__ __launch_bounds__(256) void conv1_prep(
        const u32* xu, const void* x, const void* w1, const void* b1,
        const void* wo2, const void* bo2, const void* w2, const void* b2,
        const void* wo3, const void* bo3, const void* w3, const void* b3,
        float* ws) {
    bool bf = wave_flag(xu);
    int bid = blockIdx.x;
    if (bid >= 4096) {
        int i = (bid - 4096) * 256 + threadIdx.x;
        u16* btA2 = (u16*)(ws + O_BTA2);
        u16* btB2 = (u16*)(ws + O_BTB2);
        u16* btA3 = (u16*)(ws + O_BTA3);
        u16* btB3 = (u16*)(ws + O_BTB3);
        if (i < 18432) {               // [c<18][t<2][l<64][e<8]
            int e = i & 7, l = (i >> 3) & 63, t = (i >> 9) & 1, c = i / 1024;
            int p = l & 15, q = l >> 4;
            int K = c * 32 + 8 * q + e;       // K = kk*64 + ci
            int kk = K >> 6, ci = K & 63;
            int co = t * 16 + p;
            btA2[i] = f2bf(co < 18 ? ldm(wo2, (co * 64 + ci) * 9 + kk, bf) : 0.f);
            btB2[i] = f2bf(ldm(w2, (co * 64 + ci) * 9 + kk, bf));
        }
        if (i < 9216) {                // [c<9][t<2][l<64][e<8]
            int e = i & 7, l = (i >> 3) & 63, t = (i >> 9) & 1, c = i / 1024;
            int p = l & 15, q = l >> 4;
            int K = c * 32 + 8 * q + e;       // K = kk*32 + ci
            int kk = K >> 5, ci = K & 31;
            int co = t * 16 + p;
            btA3[i] = f2bf(co < 18 ? ldm(wo3, (co * 32 + ci) * 9 + kk, bf) : 0.f);
        }
        if (i < 4608) {                // [c<9][l<64][e<8]
            int e = i & 7, l = (i >> 3) & 63, c = i / 512;
            int p = l & 15, q = l >> 4;
            int K = c * 32 + 8 * q + e;
            int kk = K >> 5, ci = K & 31;
            btB3[i] = f2bf(p < 4 ? ldm(w3, (p * 32 + ci) * 9 + kk, bf) : 0.f);
        }
        if (i < 18) ws[O_BO2 + i] = ldm(bo2, i, bf);
        if (i < 32) ws[O_B2 + i]  = ldm(b2, i, bf);
        if (i < 18) ws[O_BO3 + i] = ldm(bo3, i, bf);
        if (i < 4)  ws[O_B3 + i]  = ldm(b3, i, bf);
        return;
    }
    u16* out = (u16*)(ws + O_H1);
    int idx = bid * 256 + threadIdx.x;
    int cg = idx & 15; int t = idx >> 4;
    int xw = t & 127;  t >>= 7;
    int yh = t & 127;  int b = t >> 7;
    float xv[9];
    #pragma unroll
    for (int ky = 0; ky < 3; ++ky) {
        int yy = yh + ky - 1;
        #pragma unroll
        for (int kx = 0; kx < 3; ++kx) {
            int xx = xw + kx - 1;
            xv[ky * 3 + kx] =
                ((unsigned)yy < 128u && (unsigned)xx < 128u)
                    ? ldm(x, b * HW + yy * WW + xx, bf) : 0.f;
        }
    }
    u16 o[4];
    #pragma unroll
    for (int j = 0; j < 4; ++j) {
        int co = cg * 4 + j;
        float acc = ldm(b1, co, bf);
        #pragma unroll
        for (int k = 0; k < 9; ++k)
            acc = fmaf(ldm(w1, co * 9 + k, bf), xv[k], acc);
        o[j] = f2bf(fmaxf(acc, 0.f));
    }
    uint2 pk;
    pk.x = (u32)o[0] | ((u32)o[1] << 16);
    pk.y = (u32)o[2] | ((u32)o[3] << 16);
    *(uint2*)&out[(((size_t)b * 128 + yh) * 128 + xw) * 64 + cg * 4] = pk;
}

// =====================================================================
// fused_mid: offconv(64->18) + deform + conv(64->32) + relu, MFMA.
// Block = 512 thr (8 waves) = 2 output rows x 64 px; 6-row NHWC window.
// Weight streams per-chunk-contiguous, 3-deep prefetch.
// =====================================================================
__global__ __launch_bounds__(512) void fused_mid(
        const u16* __restrict__ h1, const u16* __restrict__ btA,
        const u16* __restrict__ btB, const float* __restrict__ bo,
        const float* __restrict__ bd, u16* __restrict__ h2) {
    __shared__ u16 win[27648];      // [6][72][64]
    __shared__ float aux[2560];     // offb[128][20]; overlay cb u16[128][32]
    int tid = threadIdx.x;
    int lane = tid & 63, p = lane & 15, q = lane >> 4;
    int wv = __builtin_amdgcn_readfirstlane(tid >> 6);
    int bid = blockIdx.x;
    int hx = bid & 1, yp = (bid >> 1) & 63, b = bid >> 7;
    int yh0 = yp * 2;
    int xwb = hx * 64, bx = xwb - 4;
    int m = wv * 16 + p;            // pixel index in block [0,128)
    int rr = m >> 6, xx = m & 63;
    const u16* h1b = h1 + (size_t)b * HW * 64;
    const u16* wA = btA + lane * 8;  // + c*1024 (+512 for tile1)
    const u16* wB = btB + lane * 8;

    // ---- stage window: 3456 uint4 slots (6 rows x 72 cols x 8 ci8) ----
    {
        uint4 st[7];
        #pragma unroll
        for (int it = 0; it < 7; ++it) {
            int s = it * 512 + tid;
            uint4 v = {0, 0, 0, 0};
            if (s < 3456) {
                int ci8 = s & 7, cc = s >> 3;
                int col = cc % 72, row = cc / 72;
                int gy = yh0 - 2 + row, gc = bx + col;
                if ((unsigned)gy < 128u && (unsigned)gc < 128u)
                    v = *(const uint4*)&h1b[((size_t)gy * 128 + gc) * 64 + ci8 * 8];
            }
            st[it] = v;
        }
        #pragma unroll
        for (int it = 0; it < 7; ++it) {
            int s = it * 512 + tid;
            if (s < 3456) {
                int ci8 = s & 7, cc = s >> 3;
                int col = cc % 72, row = cc / 72;
                *(uint4*)&win[(row * 72 + col) * 64 + ((ci8 * 8) ^ ((col & 7) << 3))]
                    = st[it];
            }
        }
    }
    __syncthreads();

    // ---- phase A: offset conv as MFMA (18 chunks), av 2-deep, w 3-deep ----
#define LDAV_M(c) (*(const short8*)&win[(((rr) + 1 + (((c) >> 1) / 3)) * 72 \
        + (xx + 3 + (((c) >> 1) % 3))) * 64 \
        + (((((c) & 1) << 5) + 8 * q) ^ (((xx + 3 + (((c) >> 1) % 3)) & 7) << 3))])
    f32x4 a0 = {0.f, 0.f, 0.f, 0.f}, a1 = {0.f, 0.f, 0.f, 0.f};
    {
        short8 avb[2], n0b[3], n1b[3];
        avb[0] = LDAV_M(0); avb[1] = LDAV_M(1);
        #pragma unroll
        for (int j = 0; j < 3; ++j) {
            n0b[j] = *(const short8*)(wA + j * 1024);
            n1b[j] = *(const short8*)(wA + j * 1024 + 512);
        }
        #pragma unroll
        for (int c = 0; c < 18; ++c) {
            short8 av = avb[c & 1], b0 = n0b[c % 3], b1 = n1b[c % 3];
            if (c + 2 < 18) avb[c & 1] = LDAV_M(c + 2);
            if (c + 3 < 18) {
                n0b[c % 3] = *(const short8*)(wA + (c + 3) * 1024);
                n1b[c % 3] = *(const short8*)(wA + (c + 3) * 1024 + 512);
            }
            a0 = __builtin_amdgcn_mfma_f32_16x16x32_bf16(av, b0, a0, 0, 0, 0);
            a1 = __builtin_amdgcn_mfma_f32_16x16x32_bf16(av, b1, a1, 0, 0, 0);
        }
    }
#undef LDAV_M
    #pragma unroll
    for (int r = 0; r < 4; ++r) {            // C: row=q*4+r, col=p
        int row = wv * 16 + q * 4 + r;
        aux[row * 20 + p] = a0[r] + bo[p];
        if (p < 2) aux[row * 20 + 16 + p] = a1[r] + bo[16 + p];
    }
    __syncthreads();

    // ---- geometry (per lane, for its pixel m) ----
    float wyA[9], wxA[9]; int pk[9];
    #pragma unroll
    for (int n = 0; n < 9; ++n) {
        float py  = aux[m * 20 + n]     + (float)(n / 3 - 1 + yh0 + rr);
        float pxf = aux[m * 20 + 9 + n] + (float)(n % 3 - 1 + xwb + xx);
        py  = fminf(fmaxf(py, 0.f), 127.f);
        pxf = fminf(fmaxf(pxf, 0.f), 127.f);
        float y0f = floorf(py), x0f = floorf(pxf);
        int y0 = (int)y0f, x0 = (int)x0f;
        int dy = (y0 < 127) ? 1 : 0, dx = (x0 < 127) ? 1 : 0;
        wyA[n] = py - y0f; wxA[n] = pxf - x0f;
        int slot = y0 - yh0 + 2, cix = x0 - bx;
        bool inw = slot >= 0 && slot + dy <= 5 && cix >= 0 && cix + dx < 72;
        pk[n] = (inw ? (cix | (slot << 7) | 4096) : 0) | (dx << 10) | (dy << 11)
              | (x0 << 13) | (y0 << 20);
    }
    __syncthreads();

    // ---- phase B: deform GEMM as MFMA, 3-buf LDS + 3-deep weights ----
#define LOADCHUNK_M(c, B) do { \
        const int n_ = (c) >> 1; \
        int ci0_ = (((c) & 1) << 5) + 8 * q; \
        int pp_ = pk[n_]; \
        int dxo_ = (pp_ >> 10) & 1, dyv_ = (pp_ >> 11) & 1; \
        if (pp_ & 4096) { \
            int cix_ = pp_ & 127, slot_ = (pp_ >> 7) & 7; \
            int colc_ = cix_ + dxo_; \
            int b00_ = (slot_ * 72 + cix_) * 64 + (ci0_ ^ ((cix_ & 7) << 3)); \
            int b01_ = (slot_ * 72 + colc_) * 64 + (ci0_ ^ ((colc_ & 7) << 3)); \
            int dro_ = dyv_ * 4608; \
            B[0] = *(const uint4*)&win[b00_]; \
            B[1] = *(const uint4*)&win[b01_]; \
            B[2] = *(const uint4*)&win[b00_ + dro_]; \
            B[3] = *(const uint4*)&win[b01_ + dro_]; \
        } else { \
            int x0_ = (pp_ >> 13) & 127, y0_ = (pp_ >> 20) & 127; \
            const u16* fp_ = h1b + ((size_t)y0_ * 128 + x0_) * 64 + ci0_; \
            B[0] = *(const uint4*)fp_; \
            B[1] = *(const uint4*)(fp_ + dxo_ * 64); \
            B[2] = *(const uint4*)(fp_ + dyv_ * 8192); \
            B[3] = *(const uint4*)(fp_ + dyv_ * 8192 + dxo_ * 64); \
        } \
    } while (0)

    f32x4 c0 = {0.f, 0.f, 0.f, 0.f}, c1 = {0.f, 0.f, 0.f, 0.f};
    {
        uint4 wbuf[3][4];
        short8 n0b[3], n1b[3];
        #pragma unroll
        for (int j = 0; j < 3; ++j) {
            n0b[j] = *(const short8*)(wB + j * 1024);
            n1b[j] = *(const short8*)(wB + j * 1024 + 512);
        }
        LOADCHUNK_M(0, wbuf[0]);
        LOADCHUNK_M(1, wbuf[1]);
        #pragma unroll
        for (int c = 0; c < 18; ++c) {
            short8 b0 = n0b[c % 3], b1 = n1b[c % 3];
            if (c + 2 < 18) LOADCHUNK_M(c + 2, wbuf[(c + 2) % 3]);
            if (c + 3 < 18) {
                n0b[c % 3] = *(const short8*)(wB + (c + 3) * 1024);
                n1b[c % 3] = *(const short8*)(wB + (c + 3) * 1024 + 512);
            }
            short8 av = bilerp8(wbuf[c % 3], wyA[c >> 1], wxA[c >> 1]);
            c0 = __builtin_amdgcn_mfma_f32_16x16x32_bf16(av, b0, c0, 0, 0, 0);
            c1 = __builtin_amdgcn_mfma_f32_16x16x32_bf16(av, b1, c1, 0, 0, 0);
        }
    }
#undef LOADCHUNK_M

    // ---- C -> LDS bounce -> coalesced NHWC h2 stores ----
    u16* cb = (u16*)aux;
    #pragma unroll
    for (int r = 0; r < 4; ++r) {
        int px = wv * 16 + q * 4 + r;
        cb[px * 32 + p]      = f2bf(fmaxf(c0[r] + bd[p], 0.f));
        cb[px * 32 + 16 + p] = f2bf(fmaxf(c1[r] + bd[16 + p], 0.f));
    }
    __syncthreads();
    {
        int px = tid >> 2, co8 = (tid & 3) * 8;
        int gy = yh0 + (px >> 6), gx = xwb + (px & 63);
        *(uint4*)&h2[(((size_t)b * 128 + gy) * 128 + gx) * 32 + co8] =
            *(const uint4*)&cb[px * 32 + co8];
    }
}

// =====================================================================
// fused_final: offconv(32->18) + deform + conv(32->4) + pixel shuffle.
// Block = 512 thr (8 waves) = 2 rows x 64 px; 6-row NHWC window [6][72][32].
// =====================================================================
__global__ __launch_bounds__(512) void fused_final(
        const u16* __restrict__ h2, const u16* __restrict__ btA,
        const u16* __restrict__ btB, const float* __restrict__ bo,
        const float* __restrict__ bd, const u32* __restrict__ xu,
        float* __restrict__ outf, u32* __restrict__ outb) {
    __shared__ u16 win[13824];      // [6][72][32]
    __shared__ float aux[2560];     // offb[128][20]; overlay ob[128][5]
    bool bf = wave_flag(xu);
    int tid = threadIdx.x;
    int lane = tid & 63, p = lane & 15, q = lane >> 4;
    int wv = __builtin_amdgcn_readfirstlane(tid >> 6);
    int bid = blockIdx.x;
    int hx = bid & 1, yp = (bid >> 1) & 63, b = bid >> 7;
    int yh0 = yp * 2;
    int xwb = hx * 64, bx = xwb - 4;
    int m = wv * 16 + p;
    int rr = m >> 6, xx = m & 63;
    const u16* h2b = h2 + (size_t)b * HW * 32;
    const u16* wA = btA + lane * 8;
    const u16* wB = btB + lane * 8;

    // ---- stage window: 1728 uint4 slots ----
    {
        uint4 st[4];
        #pragma unroll
        for (int it = 0; it < 4; ++it) {
            int s = it * 512 + tid;
            uint4 v = {0, 0, 0, 0};
            if (s < 1728) {
                int ci8 = s & 3, cc = s >> 2;
                int col = cc % 72, row = cc / 72;
                int gy = yh0 - 2 + row, gc = bx + col;
                if ((unsigned)gy < 128u && (unsigned)gc < 128u)
                    v = *(const uint4*)&h2b[((size_t)gy * 128 + gc) * 32 + ci8 * 8];
            }
            st[it] = v;
        }
        #pragma unroll
        for (int it = 0; it < 4; ++it) {
            int s = it * 512 + tid;
            if (s < 1728) {
                int ci8 = s & 3, cc = s >> 2;
                int col = cc % 72, row = cc / 72;
                *(uint4*)&win[(row * 72 + col) * 32 + ((ci8 * 8) ^ ((col & 3) << 3))]
                    = st[it];
            }
        }
    }
    __syncthreads();

    // ---- phase A (9 chunks), av 2-deep, w 3-deep ----
#define LDAV_F(c) (*(const short8*)&win[(((rr) + 1 + ((c) / 3)) * 72 \
        + (xx + 3 + ((c) % 3))) * 32 \
        + ((8 * q) ^ (((xx + 3 + ((c) % 3)) & 3) << 3))])
    f32x4 a0 = {0.f, 0.f, 0.f, 0.f}, a1 = {0.f, 0.f, 0.f, 0.f};
    {
        short8 avb[2], n0b[3], n1b[3];
        avb[0] = LDAV_F(0); avb[1] = LDAV_F(1);
        #pragma unroll
        for (int j = 0; j < 3; ++j) {
            n0b[j] = *(const short8*)(wA + j * 1024);
            n1b[j] = *(const short8*)(wA + j * 1024 + 512);
        }
        #pragma unroll
        for (int c = 0; c < 9; ++c) {
            short8 av = avb[c & 1], b0 = n0b[c % 3], b1 = n1b[c % 3];
            if (c + 2 < 9) avb[c & 1] = LDAV_F(c + 2);
            if (c + 3 < 9) {
                n0b[c % 3] = *(const short8*)(wA + (c + 3) * 1024);
                n1b[c % 3] = *(const short8*)(wA + (c + 3) * 1024 + 512);
            }
            a0 = __builtin_amdgcn_mfma_f32_16x16x32_bf16(av, b0, a0, 0, 0, 0);
            a1 = __builtin_amdgcn_mfma_f32_16x16x32_bf16(av, b1, a1, 0, 0, 0);
        }
    }
#undef LDAV_F
    #pragma unroll
    for (int r = 0; r < 4; ++r) {
        int row = wv * 16 + q * 4 + r;
        aux[row * 20 + p] = a0[r] + bo[p];
        if (p < 2) aux[row * 20 + 16 + p] = a1[r] + bo[16 + p];
    }
    __syncthreads();

    // ---- geometry ----
    float wyA[9], wxA[9]; int pk[9];
    #pragma unroll
    for (int n = 0; n < 9; ++n) {
        float py  = aux[m * 20 + n]     + (float)(n / 3 - 1 + yh0 + rr);
        float pxf = aux[m * 20 + 9 + n] + (float)(n % 3 - 1 + xwb + xx);
        py  = fminf(fmaxf(py, 0.f), 127.f);
        pxf = fminf(fmaxf(pxf, 0.f), 127.f);
        float y0f = floorf(py), x0f = floorf(pxf);
        int y0 = (int)y0f, x0 = (int)x0f;
        int dy = (y0 < 127) ? 1 : 0, dx = (x0 < 127) ? 1 : 0;
        wyA[n] = py - y0f; wxA[n] = pxf - x0f;
        int slot = y0 - yh0 + 2, cix = x0 - bx;
        bool inw = slot >= 0 && slot + dy <= 5 && cix >= 0 && cix + dx < 72;
        pk[n] = (inw ? (cix | (slot << 7) | 4096) : 0) | (dx << 10) | (dy << 11)
              | (x0 << 13) | (y0 << 20);
    }
    __syncthreads();

    // ---- phase B (9 chunks), 3-buf LDS + 3-deep weights ----
#define LOADCHUNK_F(c, B) do { \
        const int n_ = (c); \
        int ci0_ = 8 * q; \
        int pp_ = pk[n_]; \
        int dxo_ = (pp_ >> 10) & 1, dyv_ = (pp_ >> 11) & 1; \
        if (pp_ & 4096) { \
            int cix_ = pp_ & 127, slot_ = (pp_ >> 7) & 7; \
            int colc_ = cix_ + dxo_; \
            int b00_ = (slot_ * 72 + cix_) * 32 + (ci0_ ^ ((cix_ & 3) << 3)); \
            int b01_ = (slot_ * 72 + colc_) * 32 + (ci0_ ^ ((colc_ & 3) << 3)); \
            int dro_ = dyv_ * 2304; \
            B[0] = *(const uint4*)&win[b00_]; \
            B[1] = *(const uint4*)&win[b01_]; \
            B[2] = *(const uint4*)&win[b00_ + dro_]; \
            B[3] = *(const uint4*)&win[b01_ + dro_]; \
        } else { \
            int x0_ = (pp_ >> 13) & 127, y0_ = (pp_ >> 20) & 127; \
            const u16* fp_ = h2b + ((size_t)y0_ * 128 + x0_) * 32 + ci0_; \
            B[0] = *(const uint4*)fp_; \
            B[1] = *(const uint4*)(fp_ + dxo_ * 32); \
            B[2] = *(const uint4*)(fp_ + dyv_ * 4096); \
            B[3] = *(const uint4*)(fp_ + dyv_ * 4096 + dxo_ * 32); \
        } \
    } while (0)

    f32x4 c0 = {0.f, 0.f, 0.f, 0.f};
    {
        uint4 wbuf[3][4];
        short8 n0b[3];
        #pragma unroll
        for (int j = 0; j < 3; ++j)
            n0b[j] = *(const short8*)(wB + j * 512);
        LOADCHUNK_F(0, wbuf[0]);
        LOADCHUNK_F(1, wbuf[1]);
        #pragma unroll
        for (int c = 0; c < 9; ++c) {
            short8 b0 = n0b[c % 3];
            if (c + 2 < 9) LOADCHUNK_F(c + 2, wbuf[(c + 2) % 3]);
            if (c + 3 < 9) n0b[c % 3] = *(const short8*)(wB + (c + 3) * 512);
            short8 av = bilerp8(wbuf[c % 3], wyA[c], wxA[c]);
            c0 = __builtin_amdgcn_mfma_f32_16x16x32_bf16(av, b0, c0, 0, 0, 0);
        }
    }
#undef LOADCHUNK_F

    // ---- output bounce + pixel shuffle ----
    if (p < 4) {
        #pragma unroll
        for (int r = 0; r < 4; ++r)
            aux[(wv * 16 + q * 4 + r) * 5 + p] = c0[r] + bd[p];
    }
    __syncthreads();
    if (tid < 128) {
        float o0 = aux[tid * 5 + 0], o1 = aux[tid * 5 + 1];
        float o2 = aux[tid * 5 + 2], o3 = aux[tid * 5 + 3];
        int gy = yh0 + (tid >> 6), xw = xwb + (tid & 63);
        if (bf) {
            u32 p0 = ((u32)f2bf(o1) << 16) | (u32)f2bf(o0);
            u32 p1 = ((u32)f2bf(o3) << 16) | (u32)f2bf(o2);
            outb[(size_t)(b * 256 + 2 * gy) * 128 + xw]     = p0;
            outb[(size_t)(b * 256 + 2 * gy + 1) * 128 + xw] = p1;
        } else {
            size_t r0 = (size_t)(b * 256 + 2 * gy) * 256 + 2 * xw;
            outf[r0]       = o0;
            outf[r0 + 1]   = o1;
            outf[r0 + 256] = o2;
            outf[r0 + 257] = o3;
        }
    }
}

extern "C" void kernel_launch(void* const* d_in, const int* in_sizes, int n_in,
                              void* d_out, int out_size, void* d_ws, size_t ws_size,
                              hipStream_t stream) {
    float* ws = (float*)d_ws;
    const u32* xu = (const u32*)d_in[0];
    conv1_prep<<<4168, 256, 0, stream>>>(
        xu, d_in[0], d_in[1], d_in[2], d_in[3], d_in[4], d_in[5], d_in[6],
        d_in[7], d_in[8], d_in[9], d_in[10], ws);
    fused_mid<<<512, 512, 0, stream>>>(
        (const u16*)(ws + O_H1), (const u16*)(ws + O_BTA2),
        (const u16*)(ws + O_BTB2), ws + O_BO2, ws + O_B2, (u16*)(ws + O_H2));
    fused_final<<<512, 512, 0, stream>>>(
        (const u16*)(ws + O_H2), (const u16*)(ws + O_BTA3),
        (const u16*)(ws + O_BTB3), ws + O_BO3, ws + O_B3,
        xu, (float*)d_out, (u32*)d_out);
}

// Round 15
// 63.906 us; speedup vs baseline: 2.1624x; 1.4496x over previous
//
#include <hip/hip_runtime.h>

#define HH 128
#define WW 128
#define HW (HH*WW)

// ---- ws layout (f32 indices) ----
#define O_H1   0u         // u16 NHWC h1 (4,128,128,64) = 2097152 f32
#define O_H2   2097152u   // u16 NHWC h2 (4,128,128,32) = 1048576 f32
#define O_BTA2 3145728u   // u16[18*2*64*8]  offconv2, [c][tile][lane][e]
#define O_BTB2 3154944u   // u16[18*2*64*8]  deform2,  [c][tile][lane][e]
#define O_BTA3 3164160u   // u16[9*2*64*8]   offconv3, [c][tile][lane][e]
#define O_BTB3 3168768u   // u16[9*64*8]     deform3,  [c][lane][e]
#define O_BO2  3171072u
#define O_B2   3171090u
#define O_BO3  3171122u
#define O_B3   3171140u

typedef unsigned short u16;
typedef unsigned int   u32;
typedef short  short8 __attribute__((ext_vector_type(8)));
typedef float  f32x4  __attribute__((ext_vector_type(4)));
typedef float  f32x2  __attribute__((ext_vector_type(2)));

__device__ __forceinline__ float bf2f(u16 h) {
    return __uint_as_float(((u32)h) << 16);
}
__device__ __forceinline__ u16 f2bf(float f) {   // round-to-nearest-even
    u32 u = __float_as_uint(f);
    return (u16)((u + 0x7FFFu + ((u >> 16) & 1u)) >> 16);
}
__device__ __forceinline__ u32 cvtpk(float lo, float hi) {  // 2xf32 -> 2xbf16
    u32 r;
    asm("v_cvt_pk_bf16_f32 %0, %1, %2" : "=v"(r) : "v"(lo), "v"(hi));
    return r;
}
__device__ __forceinline__ void unpk2(uint4 v, f32x2* f) {
    f[0] = (f32x2){__uint_as_float(v.x << 16), __uint_as_float(v.x & 0xFFFF0000u)};
    f[1] = (f32x2){__uint_as_float(v.y << 16), __uint_as_float(v.y & 0xFFFF0000u)};
    f[2] = (f32x2){__uint_as_float(v.z << 16), __uint_as_float(v.z & 0xFFFF0000u)};
    f[3] = (f32x2){__uint_as_float(v.w << 16), __uint_as_float(v.w & 0xFFFF0000u)};
}
// bilinear on 8 packed bf16 channels -> bf16 A-fragment (packed f32 math)
__device__ __forceinline__ short8 bilerp8(const uint4* Bv, float wy, float wx) {
    f32x2 f00[4], f01[4], f10[4], f11[4];
    unpk2(Bv[0], f00); unpk2(Bv[1], f01); unpk2(Bv[2], f10); unpk2(Bv[3], f11);
    f32x2 wy2 = {wy, wy}, wx2 = {wx, wx};
    union { u32 u[4]; short8 s; } cv;
    #pragma unroll
    for (int j = 0; j < 4; ++j) {
        f32x2 top = __builtin_elementwise_fma(wx2, f01[j] - f00[j], f00[j]);
        f32x2 bot = __builtin_elementwise_fma(wx2, f11[j] - f10[j], f10[j]);
        f32x2 v   = __builtin_elementwise_fma(wy2, bot - top, top);
        cv.u[j] = cvtpk(v[0], v[1]);
    }
    return cv.s;
}
__device__ __forceinline__ float ldm(const void* p, int i, bool bf) {
    return bf ? bf2f(((const u16*)p)[i]) : ((const float*)p)[i];
}
// wave-uniform dtype flag from first 64 words of x (see round-2 notes)
__device__ __forceinline__ bool wave_flag(const u32* xu) {
    u32 w = xu[threadIdx.x & 63];
    u32 lo = w & 0xFFFFu;
    u32 e = (lo >> 7) & 0xFFu;
    bool ok = (lo != 0u) && (e >= 100u) && (e <= 140u);
    return __popcll(__ballot(ok)) > 32;
}

// =====================================================================
// conv1 + weight-prep merged. bid<256: conv1 (x -> h1 NHWC bf16, relu),
// ONE THREAD PER PIXEL: 9 coalesced x loads; weights as uniform uint4
// blocks (144B per 8-co group) unpacked with compile-time indices.
// bid>=256: weights -> bf16, per-chunk-contiguous [c][tile][lane][e].
// =====================================================================
__global__ __launch_bounds__(256) void conv1_prep(
        const u32* xu, const void* x, const void* w1, const void* b1,
        const void* wo2, const void* bo2, const void* w2, const void* b2,
        const void* wo3, const void* bo3, const void* w3, const void* b3,
        float* ws) {
    bool bf = wave_flag(xu);
    int bid = blockIdx.x;
    if (bid >= 256) {
        int i = (bid - 256) * 256 + threadIdx.x;
        u16* btA2 = (u16*)(ws + O_BTA2);
        u16* btB2 = (u16*)(ws + O_BTB2);
        u16* btA3 = (u16*)(ws + O_BTA3);
        u16* btB3 = (u16*)(ws + O_BTB3);
        if (i < 18432) {               // [c<18][t<2][l<64][e<8]
            int e = i & 7, l = (i >> 3) & 63, t = (i >> 9) & 1, c = i / 1024;
            int p = l & 15, q = l >> 4;
            int K = c * 32 + 8 * q + e;       // K = kk*64 + ci
            int kk = K >> 6, ci = K & 63;
            int co = t * 16 + p;
            btA2[i] = f2bf(co < 18 ? ldm(wo2, (co * 64 + ci) * 9 + kk, bf) : 0.f);
            btB2[i] = f2bf(ldm(w2, (co * 64 + ci) * 9 + kk, bf));
        }
        if (i < 9216) {                // [c<9][t<2][l<64][e<8]
            int e = i & 7, l = (i >> 3) & 63, t = (i >> 9) & 1, c = i / 1024;
            int p = l & 15, q = l >> 4;
            int K = c * 32 + 8 * q + e;       // K = kk*32 + ci
            int kk = K >> 5, ci = K & 31;
            int co = t * 16 + p;
            btA3[i] = f2bf(co < 18 ? ldm(wo3, (co * 32 + ci) * 9 + kk, bf) : 0.f);
        }
        if (i < 4608) {                // [c<9][l<64][e<8]
            int e = i & 7, l = (i >> 3) & 63, c = i / 512;
            int p = l & 15, q = l >> 4;
            int K = c * 32 + 8 * q + e;
            int kk = K >> 5, ci = K & 31;
            btB3[i] = f2bf(p < 4 ? ldm(w3, (p * 32 + ci) * 9 + kk, bf) : 0.f);
        }
        if (i < 18) ws[O_BO2 + i] = ldm(bo2, i, bf);
        if (i < 32) ws[O_B2 + i]  = ldm(b2, i, bf);
        if (i < 18) ws[O_BO3 + i] = ldm(bo3, i, bf);
        if (i < 4)  ws[O_B3 + i]  = ldm(b3, i, bf);
        return;
    }
    u16* out = (u16*)(ws + O_H1);
    int idx = bid * 256 + threadIdx.x;       // 65536 threads = pixels
    int xw = idx & 127; int t = idx >> 7;
    int yh = t & 127;   int b = t >> 7;
    float xv[9];
    #pragma unroll
    for (int ky = 0; ky < 3; ++ky) {
        int yy = yh + ky - 1;
        #pragma unroll
        for (int kx = 0; kx < 3; ++kx) {
            int xx = xw + kx - 1;
            xv[ky * 3 + kx] =
                ((unsigned)yy < 128u && (unsigned)xx < 128u)
                    ? ldm(x, b * HW + yy * WW + xx, bf) : 0.f;
        }
    }
    u16* obase = out + (((size_t)b * 128 + yh) * 128 + xw) * 64;
    if (bf) {
        #pragma unroll 1
        for (int cg = 0; cg < 8; ++cg) {     // 8 co per group
            const uint4* Wg = (const uint4*)w1 + cg * 9;   // 144B contiguous
            uint4 wreg[9];
            #pragma unroll
            for (int t2 = 0; t2 < 9; ++t2) wreg[t2] = Wg[t2];
            uint4 bv = ((const uint4*)b1)[cg];             // 8 bf16 biases
            const u32* wd = (const u32*)wreg;
            const u32* bd32 = (const u32*)&bv;
            u32 opk[4];
            #pragma unroll
            for (int jj = 0; jj < 4; ++jj) {
                float oo[2];
                #pragma unroll
                for (int h = 0; h < 2; ++h) {
                    int j = jj * 2 + h;
                    u32 bw = bd32[j >> 1];
                    float acc = bf2f((u16)((j & 1) ? (bw >> 16) : (bw & 0xFFFF)));
                    #pragma unroll
                    for (int k = 0; k < 9; ++k) {
                        int m = j * 9 + k;   // compile-time after unroll
                        u32 d = wd[m >> 1];
                        float wv = bf2f((u16)((m & 1) ? (d >> 16) : (d & 0xFFFF)));
                        acc = fmaf(wv, xv[k], acc);
                    }
                    oo[h] = fmaxf(acc, 0.f);
                }
                opk[jj] = cvtpk(oo[0], oo[1]);
            }
            uint4 ov = {opk[0], opk[1], opk[2], opk[3]};
            *(uint4*)&obase[cg * 8] = ov;
        }
    } else {                                 // f32 fallback (correctness)
        #pragma unroll 1
        for (int cg = 0; cg < 8; ++cg) {
            u32 opk[4];
            #pragma unroll
            for (int jj = 0; jj < 4; ++jj) {
                float oo[2];
                #pragma unroll
                for (int h = 0; h < 2; ++h) {
                    int co = cg * 8 + jj * 2 + h;
                    float acc = ldm(b1, co, false);
                    #pragma unroll
                    for (int k = 0; k < 9; ++k)
                        acc = fmaf(ldm(w1, co * 9 + k, false), xv[k], acc);
                    oo[h] = fmaxf(acc, 0.f);
                }
                opk[jj] = cvtpk(oo[0], oo[1]);
            }
            uint4 ov = {opk[0], opk[1], opk[2], opk[3]};
            *(uint4*)&obase[cg * 8] = ov;
        }
    }
}

// =====================================================================
// fused_mid: offconv(64->18) + deform + conv(64->32) + relu, MFMA.
// Block = 512 thr (8 waves) = 2 output rows x 64 px; 6-row NHWC window.
// Weight streams per-chunk-contiguous, 3-deep prefetch.
// =====================================================================
__global__ __launch_bounds__(512) void fused_mid(
        const u16* __restrict__ h1, const u16* __restrict__ btA,
        const u16* __restrict__ btB, const float* __restrict__ bo,
        const float* __restrict__ bd, u16* __restrict__ h2) {
    __shared__ u16 win[27648];      // [6][72][64]
    __shared__ float aux[2560];     // offb[128][20]; overlay cb u16[128][32]
    int tid = threadIdx.x;
    int lane = tid & 63, p = lane & 15, q = lane >> 4;
    int wv = __builtin_amdgcn_readfirstlane(tid >> 6);
    int bid = blockIdx.x;
    int hx = bid & 1, yp = (bid >> 1) & 63, b = bid >> 7;
    int yh0 = yp * 2;
    int xwb = hx * 64, bx = xwb - 4;
    int m = wv * 16 + p;            // pixel index in block [0,128)
    int rr = m >> 6, xx = m & 63;
    const u16* h1b = h1 + (size_t)b * HW * 64;
    const u16* wA = btA + lane * 8;  // + c*1024 (+512 for tile1)
    const u16* wB = btB + lane * 8;

    // ---- stage window: 3456 uint4 slots (6 rows x 72 cols x 8 ci8) ----
    {
        uint4 st[7];
        #pragma unroll
        for (int it = 0; it < 7; ++it) {
            int s = it * 512 + tid;
            uint4 v = {0, 0, 0, 0};
            if (s < 3456) {
                int ci8 = s & 7, cc = s >> 3;
                int col = cc % 72, row = cc / 72;
                int gy = yh0 - 2 + row, gc = bx + col;
                if ((unsigned)gy < 128u && (unsigned)gc < 128u)
                    v = *(const uint4*)&h1b[((size_t)gy * 128 + gc) * 64 + ci8 * 8];
            }
            st[it] = v;
        }
        #pragma unroll
        for (int it = 0; it < 7; ++it) {
            int s = it * 512 + tid;
            if (s < 3456) {
                int ci8 = s & 7, cc = s >> 3;
                int col = cc % 72, row = cc / 72;
                *(uint4*)&win[(row * 72 + col) * 64 + ((ci8 * 8) ^ ((col & 7) << 3))]
                    = st[it];
            }
        }
    }
    __syncthreads();

    // ---- phase A: offset conv as MFMA (18 chunks), av 2-deep, w 3-deep ----
#define LDAV_M(c) (*(const short8*)&win[(((rr) + 1 + (((c) >> 1) / 3)) * 72 \
        + (xx + 3 + (((c) >> 1) % 3))) * 64 \
        + (((((c) & 1) << 5) + 8 * q) ^ (((xx + 3 + (((c) >> 1) % 3)) & 7) << 3))])
    f32x4 a0 = {0.f, 0.f, 0.f, 0.f}, a1 = {0.f, 0.f, 0.f, 0.f};
    {
        short8 avb[2], n0b[3], n1b[3];
        avb[0] = LDAV_M(0); avb[1] = LDAV_M(1);
        #pragma unroll
        for (int j = 0; j < 3; ++j) {
            n0b[j] = *(const short8*)(wA + j * 1024);
            n1b[j] = *(const short8*)(wA + j * 1024 + 512);
        }
        #pragma unroll
        for (int c = 0; c < 18; ++c) {
            short8 av = avb[c & 1], b0 = n0b[c % 3], b1 = n1b[c % 3];
            if (c + 2 < 18) avb[c & 1] = LDAV_M(c + 2);
            if (c + 3 < 18) {
                n0b[c % 3] = *(const short8*)(wA + (c + 3) * 1024);
                n1b[c % 3] = *(const short8*)(wA + (c + 3) * 1024 + 512);
            }
            a0 = __builtin_amdgcn_mfma_f32_16x16x32_bf16(av, b0, a0, 0, 0, 0);
            a1 = __builtin_amdgcn_mfma_f32_16x16x32_bf16(av, b1, a1, 0, 0, 0);
        }
    }
#undef LDAV_M
    #pragma unroll
    for (int r = 0; r < 4; ++r) {            // C: row=q*4+r, col=p
        int row = wv * 16 + q * 4 + r;
        aux[row * 20 + p] = a0[r] + bo[p];
        if (p < 2) aux[row * 20 + 16 + p] = a1[r] + bo[16 + p];
    }
    __syncthreads();

    // ---- geometry (per lane, for its pixel m) ----
    float wyA[9], wxA[9]; int pk[9];
    #pragma unroll
    for (int n = 0; n < 9; ++n) {
        float py  = aux[m * 20 + n]     + (float)(n / 3 - 1 + yh0 + rr);
        float pxf = aux[m * 20 + 9 + n] + (float)(n % 3 - 1 + xwb + xx);
        py  = fminf(fmaxf(py, 0.f), 127.f);
        pxf = fminf(fmaxf(pxf, 0.f), 127.f);
        float y0f = floorf(py), x0f = floorf(pxf);
        int y0 = (int)y0f, x0 = (int)x0f;
        int dy = (y0 < 127) ? 1 : 0, dx = (x0 < 127) ? 1 : 0;
        wyA[n] = py - y0f; wxA[n] = pxf - x0f;
        int slot = y0 - yh0 + 2, cix = x0 - bx;
        bool inw = slot >= 0 && slot + dy <= 5 && cix >= 0 && cix + dx < 72;
        pk[n] = (inw ? (cix | (slot << 7) | 4096) : 0) | (dx << 10) | (dy << 11)
              | (x0 << 13) | (y0 << 20);
    }
    __syncthreads();

    // ---- phase B: deform GEMM as MFMA, 3-buf LDS + 3-deep weights ----
#define LOADCHUNK_M(c, B) do { \
        const int n_ = (c) >> 1; \
        int ci0_ = (((c) & 1) << 5) + 8 * q; \
        int pp_ = pk[n_]; \
        int dxo_ = (pp_ >> 10) & 1, dyv_ = (pp_ >> 11) & 1; \
        if (pp_ & 4096) { \
            int cix_ = pp_ & 127, slot_ = (pp_ >> 7) & 7; \
            int colc_ = cix_ + dxo_; \
            int b00_ = (slot_ * 72 + cix_) * 64 + (ci0_ ^ ((cix_ & 7) << 3)); \
            int b01_ = (slot_ * 72 + colc_) * 64 + (ci0_ ^ ((colc_ & 7) << 3)); \
            int dro_ = dyv_ * 4608; \
            B[0] = *(const uint4*)&win[b00_]; \
            B[1] = *(const uint4*)&win[b01_]; \
            B[2] = *(const uint4*)&win[b00_ + dro_]; \
            B[3] = *(const uint4*)&win[b01_ + dro_]; \
        } else { \
            int x0_ = (pp_ >> 13) & 127, y0_ = (pp_ >> 20) & 127; \
            const u16* fp_ = h1b + ((size_t)y0_ * 128 + x0_) * 64 + ci0_; \
            B[0] = *(const uint4*)fp_; \
            B[1] = *(const uint4*)(fp_ + dxo_ * 64); \
            B[2] = *(const uint4*)(fp_ + dyv_ * 8192); \
            B[3] = *(const uint4*)(fp_ + dyv_ * 8192 + dxo_ * 64); \
        } \
    } while (0)

    f32x4 c0 = {0.f, 0.f, 0.f, 0.f}, c1 = {0.f, 0.f, 0.f, 0.f};
    {
        uint4 wbuf[3][4];
        short8 n0b[3], n1b[3];
        #pragma unroll
        for (int j = 0; j < 3; ++j) {
            n0b[j] = *(const short8*)(wB + j * 1024);
            n1b[j] = *(const short8*)(wB + j * 1024 + 512);
        }
        LOADCHUNK_M(0, wbuf[0]);
        LOADCHUNK_M(1, wbuf[1]);
        #pragma unroll
        for (int c = 0; c < 18; ++c) {
            short8 b0 = n0b[c % 3], b1 = n1b[c % 3];
            if (c + 2 < 18) LOADCHUNK_M(c + 2, wbuf[(c + 2) % 3]);
            if (c + 3 < 18) {
                n0b[c % 3] = *(const short8*)(wB + (c + 3) * 1024);
                n1b[c % 3] = *(const short8*)(wB + (c + 3) * 1024 + 512);
            }
            short8 av = bilerp8(wbuf[c % 3], wyA[c >> 1], wxA[c >> 1]);
            c0 = __builtin_amdgcn_mfma_f32_16x16x32_bf16(av, b0, c0, 0, 0, 0);
            c1 = __builtin_amdgcn_mfma_f32_16x16x32_bf16(av, b1, c1, 0, 0, 0);
        }
    }
#undef LOADCHUNK_M

    // ---- C -> LDS bounce -> coalesced NHWC h2 stores ----
    u16* cb = (u16*)aux;
    #pragma unroll
    for (int r = 0; r < 4; ++r) {
        int px = wv * 16 + q * 4 + r;
        cb[px * 32 + p]      = f2bf(fmaxf(c0[r] + bd[p], 0.f));
        cb[px * 32 + 16 + p] = f2bf(fmaxf(c1[r] + bd[16 + p], 0.f));
    }
    __syncthreads();
    {
        int px = tid >> 2, co8 = (tid & 3) * 8;
        int gy = yh0 + (px >> 6), gx = xwb + (px & 63);
        *(uint4*)&h2[(((size_t)b * 128 + gy) * 128 + gx) * 32 + co8] =
            *(const uint4*)&cb[px * 32 + co8];
    }
}

// =====================================================================
// fused_final: offconv(32->18) + deform + conv(32->4) + pixel shuffle.
// Block = 512 thr (8 waves) = 2 rows x 64 px; 6-row NHWC window [6][72][32].
// =====================================================================
__global__ __launch_bounds__(512) void fused_final(
        const u16* __restrict__ h2, const u16* __restrict__ btA,
        const u16* __restrict__ btB, const float* __restrict__ bo,
        const float* __restrict__ bd, const u32* __restrict__ xu,
        float* __restrict__ outf, u32* __restrict__ outb) {
    __shared__ u16 win[13824];      // [6][72][32]
    __shared__ float aux[2560];     // offb[128][20]; overlay ob[128][5]
    bool bf = wave_flag(xu);
    int tid = threadIdx.x;
    int lane = tid & 63, p = lane & 15, q = lane >> 4;
    int wv = __builtin_amdgcn_readfirstlane(tid >> 6);
    int bid = blockIdx.x;
    int hx = bid & 1, yp = (bid >> 1) & 63, b = bid >> 7;
    int yh0 = yp * 2;
    int xwb = hx * 64, bx = xwb - 4;
    int m = wv * 16 + p;
    int rr = m >> 6, xx = m & 63;
    const u16* h2b = h2 + (size_t)b * HW * 32;
    const u16* wA = btA + lane * 8;
    const u16* wB = btB + lane * 8;

    // ---- stage window: 1728 uint4 slots ----
    {
        uint4 st[4];
        #pragma unroll
        for (int it = 0; it < 4; ++it) {
            int s = it * 512 + tid;
            uint4 v = {0, 0, 0, 0};
            if (s < 1728) {
                int ci8 = s & 3, cc = s >> 2;
                int col = cc % 72, row = cc / 72;
                int gy = yh0 - 2 + row, gc = bx + col;
                if ((unsigned)gy < 128u && (unsigned)gc < 128u)
                    v = *(const uint4*)&h2b[((size_t)gy * 128 + gc) * 32 + ci8 * 8];
            }
            st[it] = v;
        }
        #pragma unroll
        for (int it = 0; it < 4; ++it) {
            int s = it * 512 + tid;
            if (s < 1728) {
                int ci8 = s & 3, cc = s >> 2;
                int col = cc % 72, row = cc / 72;
                *(uint4*)&win[(row * 72 + col) * 32 + ((ci8 * 8) ^ ((col & 3) << 3))]
                    = st[it];
            }
        }
    }
    __syncthreads();

    // ---- phase A (9 chunks), av 2-deep, w 3-deep ----
#define LDAV_F(c) (*(const short8*)&win[(((rr) + 1 + ((c) / 3)) * 72 \
        + (xx + 3 + ((c) % 3))) * 32 \
        + ((8 * q) ^ (((xx + 3 + ((c) % 3)) & 3) << 3))])
    f32x4 a0 = {0.f, 0.f, 0.f, 0.f}, a1 = {0.f, 0.f, 0.f, 0.f};
    {
        short8 avb[2], n0b[3], n1b[3];
        avb[0] = LDAV_F(0); avb[1] = LDAV_F(1);
        #pragma unroll
        for (int j = 0; j < 3; ++j) {
            n0b[j] = *(const short8*)(wA + j * 1024);
            n1b[j] = *(const short8*)(wA + j * 1024 + 512);
        }
        #pragma unroll
        for (int c = 0; c < 9; ++c) {
            short8 av = avb[c & 1], b0 = n0b[c % 3], b1 = n1b[c % 3];
            if (c + 2 < 9) avb[c & 1] = LDAV_F(c + 2);
            if (c + 3 < 9) {
                n0b[c % 3] = *(const short8*)(wA + (c + 3) * 1024);
                n1b[c % 3] = *(const short8*)(wA + (c + 3) * 1024 + 512);
            }
            a0 = __builtin_amdgcn_mfma_f32_16x16x32_bf16(av, b0, a0, 0, 0, 0);
            a1 = __builtin_amdgcn_mfma_f32_16x16x32_bf16(av, b1, a1, 0, 0, 0);
        }
    }
#undef LDAV_F
    #pragma unroll
    for (int r = 0; r < 4; ++r) {
        int row = wv * 16 + q * 4 + r;
        aux[row * 20 + p] = a0[r] + bo[p];
        if (p < 2) aux[row * 20 + 16 + p] = a1[r] + bo[16 + p];
    }
    __syncthreads();

    // ---- geometry ----
    float wyA[9], wxA[9]; int pk[9];
    #pragma unroll
    for (int n = 0; n < 9; ++n) {
        float py  = aux[m * 20 + n]     + (float)(n / 3 - 1 + yh0 + rr);
        float pxf = aux[m * 20 + 9 + n] + (float)(n % 3 - 1 + xwb + xx);
        py  = fminf(fmaxf(py, 0.f), 127.f);
        pxf = fminf(fmaxf(pxf, 0.f), 127.f);
        float y0f = floorf(py), x0f = floorf(pxf);
        int y0 = (int)y0f, x0 = (int)x0f;
        int dy = (y0 < 127) ? 1 : 0, dx = (x0 < 127) ? 1 : 0;
        wyA[n] = py - y0f; wxA[n] = pxf - x0f;
        int slot = y0 - yh0 + 2, cix = x0 - bx;
        bool inw = slot >= 0 && slot + dy <= 5 && cix >= 0 && cix + dx < 72;
        pk[n] = (inw ? (cix | (slot << 7) | 4096) : 0) | (dx << 10) | (dy << 11)
              | (x0 << 13) | (y0 << 20);
    }
    __syncthreads();

    // ---- phase B (9 chunks), 3-buf LDS + 3-deep weights ----
#define LOADCHUNK_F(c, B) do { \
        const int n_ = (c); \
        int ci0_ = 8 * q; \
        int pp_ = pk[n_]; \
        int dxo_ = (pp_ >> 10) & 1, dyv_ = (pp_ >> 11) & 1; \
        if (pp_ & 4096) { \
            int cix_ = pp_ & 127, slot_ = (pp_ >> 7) & 7; \
            int colc_ = cix_ + dxo_; \
            int b00_ = (slot_ * 72 + cix_) * 32 + (ci0_ ^ ((cix_ & 3) << 3)); \
            int b01_ = (slot_ * 72 + colc_) * 32 + (ci0_ ^ ((colc_ & 3) << 3)); \
            int dro_ = dyv_ * 2304; \
            B[0] = *(const uint4*)&win[b00_]; \
            B[1] = *(const uint4*)&win[b01_]; \
            B[2] = *(const uint4*)&win[b00_ + dro_]; \
            B[3] = *(const uint4*)&win[b01_ + dro_]; \
        } else { \
            int x0_ = (pp_ >> 13) & 127, y0_ = (pp_ >> 20) & 127; \
            const u16* fp_ = h2b + ((size_t)y0_ * 128 + x0_) * 32 + ci0_; \
            B[0] = *(const uint4*)fp_; \
            B[1] = *(const uint4*)(fp_ + dxo_ * 32); \
            B[2] = *(const uint4*)(fp_ + dyv_ * 4096); \
            B[3] = *(const uint4*)(fp_ + dyv_ * 4096 + dxo_ * 32); \
        } \
    } while (0)

    f32x4 c0 = {0.f, 0.f, 0.f, 0.f};
    {
        uint4 wbuf[3][4];
        short8 n0b[3];
        #pragma unroll
        for (int j = 0; j < 3; ++j)
            n0b[j] = *(const short8*)(wB + j * 512);
        LOADCHUNK_F(0, wbuf[0]);
        LOADCHUNK_F(1, wbuf[1]);
        #pragma unroll
        for (int c = 0; c < 9; ++c) {
            short8 b0 = n0b[c % 3];
            if (c + 2 < 9) LOADCHUNK_F(c + 2, wbuf[(c + 2) % 3]);
            if (c + 3 < 9) n0b[c % 3] = *(const short8*)(wB + (c + 3) * 512);
            short8 av = bilerp8(wbuf[c % 3], wyA[c], wxA[c]);
            c0 = __builtin_amdgcn_mfma_f32_16x16x32_bf16(av, b0, c0, 0, 0, 0);
        }
    }
#undef LOADCHUNK_F

    // ---- output bounce + pixel shuffle ----
    if (p < 4) {
        #pragma unroll
        for (int r = 0; r < 4; ++r)
            aux[(wv * 16 + q * 4 + r) * 5 + p] = c0[r] + bd[p];
    }
    __syncthreads();
    if (tid < 128) {
        float o0 = aux[tid * 5 + 0], o1 = aux[tid * 5 + 1];
        float o2 = aux[tid * 5 + 2], o3 = aux[tid * 5 + 3];
        int gy = yh0 + (tid >> 6), xw = xwb + (tid & 63);
        if (bf) {
            u32 p0 = ((u32)f2bf(o1) << 16) | (u32)f2bf(o0);
            u32 p1 = ((u32)f2bf(o3) << 16) | (u32)f2bf(o2);
            outb[(size_t)(b * 256 + 2 * gy) * 128 + xw]     = p0;
            outb[(size_t)(b * 256 + 2 * gy + 1) * 128 + xw] = p1;
        } else {
            size_t r0 = (size_t)(b * 256 + 2 * gy) * 256 + 2 * xw;
            outf[r0]       = o0;
            outf[r0 + 1]   = o1;
            outf[r0 + 256] = o2;
            outf[r0 + 257] = o3;
        }
    }
}

extern "C" void kernel_launch(void* const* d_in, const int* in_sizes, int n_in,
                              void* d_out, int out_size, void* d_ws, size_t ws_size,
                              hipStream_t stream) {
    float* ws = (float*)d_ws;
    const u32* xu = (const u32*)d_in[0];
    conv1_prep<<<328, 256, 0, stream>>>(
        xu, d_in[0], d_in[1], d_in[2], d_in[3], d_in[4], d_in[5], d_in[6],
        d_in[7], d_in[8], d_in[9], d_in[10], ws);
    fused_mid<<<512, 512, 0, stream>>>(
        (const u16*)(ws + O_H1), (const u16*)(ws + O_BTA2),
        (const u16*)(ws + O_BTB2), ws + O_BO2, ws + O_B2, (u16*)(ws + O_H2));
    fused_final<<<512, 512, 0, stream>>>(
        (const u16*)(ws + O_H2), (const u16*)(ws + O_BTA3),
        (const u16*)(ws + O_BTB3), ws + O_BO3, ws + O_B3,
        xu, (float*)d_out, (u32*)d_out);
}